// Round 14
// baseline (643.422 us; speedup 1.0000x reference)
//
#include <hip/hip_runtime.h>

// 2-layer LSTM (H=64, D=1), N=2048, T=512 — MFMA bf16 3-term split precision.
// R14 = R13 + MFMA LOAD REBALANCE (E/O 24/48 -> 36/36):
//  E additionally computes PA(k-1) = Wih2[K-half0]·h1(k-1) (12 MFMAs, reusing
//  the B-fragments it already loads for L1) and writes the f32 partial to a
//  double-buffered LDS buffer; O consumes PA two intervals later (off the
//  critical path) and drops to Wih2-half1 (12) + Whh2 (24) = 36 MFMAs + add.
//  h1 planes become 4-slot (O reads at lag 2 while E writes lag 0); h2 2-slot.
//  All LDS plane addresses are compile-time ds-offset immediates via 4-way
//  parity-specialized unroll (no hoisted-address register arrays).
// 128 blocks x 512 threads (8 waves, 2/SIMD). One __syncthreads per step.

typedef __attribute__((ext_vector_type(8))) short short8;
typedef __attribute__((ext_vector_type(4))) float f32x4;

#define XPITCH 2060              // 515 words (odd) -> conflict-free x reads
#define XP 0                     // 16 * 2060 = 32960
#define H1B 32960                // 4 slots x (hi,lo) x 2304 = 18432
#define H1(S, HL) (H1B + (S) * 4608 + (HL) * 2304)
#define H2B 51392                // 2 slots x (hi,lo) x 2304 = 9216
#define H2(Q, HL) (H2B + (Q) * 4608 + (HL) * 2304)
#define PBB 60608                // 2 bufs x 16 rows x 1280 = 40960
#define RING 101568              // 128 slots * 256 B
#define LDS_BYTES 134336
#define L2E 1.44269504f
#define N2L2E (-2.8853900817779268f)

__device__ __forceinline__ float fast_rcp(float x) { return __builtin_amdgcn_rcpf(x); }
__device__ __forceinline__ float exp2_f(float x) {
  float r; asm("v_exp_f32 %0, %1" : "=v"(r) : "v"(x)); return r;
}
__device__ __forceinline__ unsigned short bf_rne(float f) {
  unsigned u = __float_as_uint(f);
  return (unsigned short)((u + 0x7FFFu + ((u >> 16) & 1u)) >> 16);
}
__device__ __forceinline__ void split8sc(const float* p, float sc, short8& hi, short8& lo) {
#pragma unroll
  for (int e = 0; e < 8; ++e) {
    float v = p[e] * sc;
    unsigned short h = bf_rne(v);
    float hf = __uint_as_float(((unsigned)h) << 16);
    hi[e] = (short)h;
    lo[e] = (short)bf_rne(v - hf);
  }
}
__device__ __forceinline__ unsigned cvt_pk(float a, float b) {
  unsigned r;
  asm("v_cvt_pk_bf16_f32 %0, %1, %2" : "=v"(r) : "v"(a), "v"(b));
  return r;
}
__device__ __forceinline__ f32x4 mfma16(short8 a, short8 b, f32x4 c) {
  return __builtin_amdgcn_mfma_f32_16x16x32_bf16(a, b, c, 0, 0, 0);
}
// gates pre-scaled: i,f,o by log2e; g by 2log2e. 5 exp2 + 3 rcp.
__device__ __forceinline__ void cell2(float i, float f, float g, float o,
                                      float& c, float& h) {
  const float ei = exp2_f(-i), ef = exp2_f(-f), eg = exp2_f(-g), eo = exp2_f(-o);
  const float P = (1.f - eg) * fast_rcp((1.f + ei) * (1.f + eg));
  c = fmaf(c, fast_rcp(1.f + ef), P);
  const float cc = fminf(15.f, fmaxf(-15.f, c));
  const float ec = exp2_f(N2L2E * cc);
  h = (1.f - ec) * fast_rcp((1.f + eo) * (1.f + ec));
}

__global__ __launch_bounds__(512, 2) void lstm2_r14(
    const float* __restrict__ y, const float* __restrict__ Wih1,
    const float* __restrict__ Whh1, const float* __restrict__ bih1,
    const float* __restrict__ bhh1, const float* __restrict__ Wih2,
    const float* __restrict__ Whh2, const float* __restrict__ bih2,
    const float* __restrict__ bhh2, const float* __restrict__ Wlin,
    const float* __restrict__ blin, float* __restrict__ out) {
  extern __shared__ char smem[];
  const int tid = threadIdx.x;
  const int w = tid >> 6;          // wave 0..7
  const int lane = tid & 63;
  const int g = lane >> 4;
  const int s = lane & 15;
  const int s0 = blockIdx.x * 16;

  for (int i = tid; i < 16 * 512; i += 512) {
    const int ss = i >> 9, t = i & 511;
    *(float*)(smem + XP + ss * XPITCH + t * 4) = y[(size_t)(s0 + ss) * 512 + t];
  }
  for (int i = tid; i < 27648 / 4; i += 512)   // zero h1 (4 slots) + h2 (2 slots)
    *(float*)(smem + H1B + i * 4) = 0.f;
  const float bl0 = blin[0];
  __syncthreads();

  const int bo0 = s * 144 + 16 * g, bo1 = bo0 + 64;
  const float gsc[4] = {L2E, L2E, 2.0f * L2E, L2E};
  const f32x4 zero4 = {0.f, 0.f, 0.f, 0.f};

  if (w < 4) {
    // ============ E: L1(k) + PA(k-1) = Wih2-half0 . h1(k-1) ============
    const int row = 16 * w + s;
    short8 a1h[4][2], a1l[4][2], aPh[4], aPl[4];
#pragma unroll
    for (int p = 0; p < 4; ++p) {
#pragma unroll
      for (int c = 0; c < 2; ++c)
        split8sc(Whh1 + (size_t)(p * 64 + row) * 64 + 32 * c + 8 * g, gsc[p],
                 a1h[p][c], a1l[p][c]);
      split8sc(Wih2 + (size_t)(p * 64 + row) * 64 + 8 * g, gsc[p], aPh[p], aPl[p]);
    }
    float bias1c[4][4], wih1c[4][4];
#pragma unroll
    for (int p = 0; p < 4; ++p)
#pragma unroll
      for (int r = 0; r < 4; ++r) {
        const int rr = p * 64 + 16 * w + 4 * g + r;
        bias1c[p][r] = (bih1[rr] + bhh1[rr]) * gsc[p];
        wih1c[p][r] = Wih1[rr] * gsc[p];
      }
    float c1[4] = {0.f, 0.f, 0.f, 0.f};
    const int hwr0 = s * 144 + 32 * w + 8 * g;
    const float* xrow = (const float*)(smem + XP + s * XPITCH);
    char* pb0 = smem + PBB + w * 1280 + lane * 16 + (lane >> 3) * 16;
    char* pb1 = pb0 + 20480;

#define EB(KK, S)                                                             \
  {                                                                           \
    const float x = xrow[KK];                                                 \
    const short8 Bh0 = *(const short8*)(smem + H1(((S) + 3) & 3, 0) + bo0);   \
    const short8 Bl0 = *(const short8*)(smem + H1(((S) + 3) & 3, 1) + bo0);   \
    const short8 Bh1 = *(const short8*)(smem + H1(((S) + 3) & 3, 0) + bo1);   \
    const short8 Bl1 = *(const short8*)(smem + H1(((S) + 3) & 3, 1) + bo1);   \
    f32x4 acc[4];                                                             \
    _Pragma("unroll") for (int p = 0; p < 4; ++p) {                           \
      _Pragma("unroll") for (int r = 0; r < 4; ++r)                           \
          acc[p][r] = fmaf(wih1c[p][r], x, bias1c[p][r]);                     \
    }                                                                         \
    __builtin_amdgcn_s_setprio(1);                                            \
    _Pragma("unroll") for (int p = 0; p < 4; ++p)                             \
        acc[p] = mfma16(a1h[p][0], Bh0, acc[p]);                              \
    _Pragma("unroll") for (int p = 0; p < 4; ++p)                             \
        acc[p] = mfma16(a1h[p][1], Bh1, acc[p]);                              \
    _Pragma("unroll") for (int p = 0; p < 4; ++p)                             \
        acc[p] = mfma16(a1h[p][0], Bl0, acc[p]);                              \
    _Pragma("unroll") for (int p = 0; p < 4; ++p)                             \
        acc[p] = mfma16(a1h[p][1], Bl1, acc[p]);                              \
    _Pragma("unroll") for (int p = 0; p < 4; ++p)                             \
        acc[p] = mfma16(a1l[p][0], Bh0, acc[p]);                              \
    _Pragma("unroll") for (int p = 0; p < 4; ++p)                             \
        acc[p] = mfma16(a1l[p][1], Bh1, acc[p]);                              \
    if ((KK) >= 1) {                                                          \
      f32x4 ap[4];                                                            \
      _Pragma("unroll") for (int p = 0; p < 4; ++p)                           \
          ap[p] = mfma16(aPl[p], Bh0, zero4);                                 \
      _Pragma("unroll") for (int p = 0; p < 4; ++p)                           \
          ap[p] = mfma16(aPh[p], Bl0, ap[p]);                                 \
      _Pragma("unroll") for (int p = 0; p < 4; ++p)                           \
          ap[p] = mfma16(aPh[p], Bh0, ap[p]);                                 \
      char* pw = ((((S) + 1) & 1) ? pb1 : pb0);                               \
      _Pragma("unroll") for (int p = 0; p < 4; ++p)                           \
          *(f32x4*)(pw + p * 5120) = ap[p];                                   \
    }                                                                         \
    __builtin_amdgcn_s_setprio(0);                                            \
    float h1n[4];                                                             \
    _Pragma("unroll") for (int r = 0; r < 4; ++r)                             \
        cell2(acc[0][r], acc[1][r], acc[2][r], acc[3][r], c1[r], h1n[r]);     \
    const unsigned hA = cvt_pk(h1n[0], h1n[1]), hB = cvt_pk(h1n[2], h1n[3]);  \
    const unsigned lA = cvt_pk(h1n[0] - __uint_as_float(hA << 16),            \
                               h1n[1] - __uint_as_float(hA & 0xFFFF0000u));   \
    const unsigned lB = cvt_pk(h1n[2] - __uint_as_float(hB << 16),            \
                               h1n[3] - __uint_as_float(hB & 0xFFFF0000u));   \
    *(uint2*)(smem + H1((S), 0) + hwr0) = make_uint2(hA, hB);                 \
    *(uint2*)(smem + H1((S), 1) + hwr0) = make_uint2(lA, lB);                 \
  }

#pragma unroll 1
    for (int kb = 0; kb < 512; kb += 4) {
      EB(kb + 0, 0);
      __syncthreads();
      EB(kb + 1, 1);
      __syncthreads();
      EB(kb + 2, 2);
      __syncthreads();
      EB(kb + 3, 3);
      __syncthreads();
    }
    {  // iter 512: PA(511) only (h1(511) in slot 3, write parity 1)
      const short8 Bh0 = *(const short8*)(smem + H1(3, 0) + bo0);
      const short8 Bl0 = *(const short8*)(smem + H1(3, 1) + bo0);
      f32x4 ap[4];
#pragma unroll
      for (int p = 0; p < 4; ++p) ap[p] = mfma16(aPl[p], Bh0, zero4);
#pragma unroll
      for (int p = 0; p < 4; ++p) ap[p] = mfma16(aPh[p], Bl0, ap[p]);
#pragma unroll
      for (int p = 0; p < 4; ++p) ap[p] = mfma16(aPh[p], Bh0, ap[p]);
#pragma unroll
      for (int p = 0; p < 4; ++p) *(f32x4*)(pb1 + p * 5120) = ap[p];
    }
    __syncthreads();  // iter 512 barrier
    __syncthreads();  // iter 513 barrier (E idle)
  } else {
    // ============ O: L2(k-2) = PA + Wih2-half1.h1(k-2) + Whh2.h2(k-3) ======
    const int ow = w - 4;
    const int row = 16 * ow + s;
    short8 a2h1[4], a2l1[4], ahh[4][2], all_[4][2];
#pragma unroll
    for (int p = 0; p < 4; ++p) {
      split8sc(Wih2 + (size_t)(p * 64 + row) * 64 + 32 + 8 * g, gsc[p],
               a2h1[p], a2l1[p]);
#pragma unroll
      for (int c = 0; c < 2; ++c)
        split8sc(Whh2 + (size_t)(p * 64 + row) * 64 + 32 * c + 8 * g, gsc[p],
                 ahh[p][c], all_[p][c]);
    }
    f32x4 bias2v[4];
    float wlinc[4];
#pragma unroll
    for (int p = 0; p < 4; ++p)
#pragma unroll
      for (int r = 0; r < 4; ++r) {
        const int rr = p * 64 + 16 * ow + 4 * g + r;
        bias2v[p][r] = (bih2[rr] + bhh2[rr]) * gsc[p];
      }
#pragma unroll
    for (int r = 0; r < 4; ++r) wlinc[r] = Wlin[16 * ow + 4 * g + r];
    float c2[4] = {0.f, 0.f, 0.f, 0.f};
    const int hwr0 = s * 144 + 32 * ow + 8 * g;
    const char* po0 = smem + PBB + ow * 1280 + lane * 16 + (lane >> 3) * 16;
    const char* po1 = po0 + 20480;
    char* ringb = smem + RING + ow * 64 + s * 4;

#define OFLUSH(KK)                                                            \
  if ((KK) >= 67 && (((KK) - 3) & 63) == 0) {                                 \
    const int base = (KK) - 67;                                               \
    const int thr = ow * 64 + lane;                                           \
    const int ss2 = thr & 15, grp = thr >> 4;                                 \
    _Pragma("unroll") for (int q = 0; q < 4; ++q) {                           \
      const int idx = base + grp * 4 + q;                                     \
      const char* op = smem + RING + (idx & 127) * 256 + ss2 * 4;             \
      const float v = *(const float*)(op) + *(const float*)(op + 64) +        \
                      *(const float*)(op + 128) + *(const float*)(op + 192) + \
                      bl0;                                                    \
      out[(size_t)(s0 + ss2) * 511 + idx] = v;                                \
    }                                                                         \
  }

#define OB(KK, S)                                                             \
  {                                                                           \
    OFLUSH(KK);                                                               \
    if ((KK) >= 2) {                                                          \
      const char* pr = (((S) & 1) ? po1 : po0);                               \
      f32x4 pa[4];                                                            \
      _Pragma("unroll") for (int p = 0; p < 4; ++p)                           \
          pa[p] = *(const f32x4*)(pr + p * 5120);                             \
      const short8 Bh1 = *(const short8*)(smem + H1(((S) + 2) & 3, 0) + bo1); \
      const short8 Bl1 = *(const short8*)(smem + H1(((S) + 2) & 3, 1) + bo1); \
      const short8 Ch0 = *(const short8*)(smem + H2(((S) + 1) & 1, 0) + bo0); \
      const short8 Cl0 = *(const short8*)(smem + H2(((S) + 1) & 1, 1) + bo0); \
      const short8 Ch1 = *(const short8*)(smem + H2(((S) + 1) & 1, 0) + bo1); \
      const short8 Cl1 = *(const short8*)(smem + H2(((S) + 1) & 1, 1) + bo1); \
      f32x4 acc[4], acx[4];                                                   \
      __builtin_amdgcn_s_setprio(1);                                          \
      _Pragma("unroll") for (int p = 0; p < 4; ++p)                           \
          acc[p] = mfma16(a2h1[p], Bh1, bias2v[p]);                           \
      _Pragma("unroll") for (int p = 0; p < 4; ++p)                           \
          acx[p] = mfma16(ahh[p][0], Ch0, zero4);                             \
      _Pragma("unroll") for (int p = 0; p < 4; ++p)                           \
          acc[p] = mfma16(a2h1[p], Bl1, acc[p]);                              \
      _Pragma("unroll") for (int p = 0; p < 4; ++p)                           \
          acx[p] = mfma16(ahh[p][1], Ch1, acx[p]);                            \
      _Pragma("unroll") for (int p = 0; p < 4; ++p)                           \
          acc[p] = mfma16(a2l1[p], Bh1, acc[p]);                              \
      _Pragma("unroll") for (int p = 0; p < 4; ++p)                           \
          acx[p] = mfma16(ahh[p][0], Cl0, acx[p]);                            \
      _Pragma("unroll") for (int p = 0; p < 4; ++p)                           \
          acc[p] = mfma16(all_[p][0], Ch0, acc[p]);                           \
      _Pragma("unroll") for (int p = 0; p < 4; ++p)                           \
          acx[p] = mfma16(ahh[p][1], Cl1, acx[p]);                            \
      _Pragma("unroll") for (int p = 0; p < 4; ++p)                           \
          acc[p] = mfma16(all_[p][1], Ch1, acc[p]);                           \
      __builtin_amdgcn_s_setprio(0);                                          \
      float h2n[4];                                                           \
      _Pragma("unroll") for (int r = 0; r < 4; ++r) {                         \
        const float gi = acc[0][r] + acx[0][r] + pa[0][r];                    \
        const float gf = acc[1][r] + acx[1][r] + pa[1][r];                    \
        const float gg = acc[2][r] + acx[2][r] + pa[2][r];                    \
        const float go = acc[3][r] + acx[3][r] + pa[3][r];                    \
        cell2(gi, gf, gg, go, c2[r], h2n[r]);                                 \
      }                                                                       \
      const unsigned hA = cvt_pk(h2n[0], h2n[1]), hB = cvt_pk(h2n[2], h2n[3]);\
      const unsigned lA = cvt_pk(h2n[0] - __uint_as_float(hA << 16),          \
                                 h2n[1] - __uint_as_float(hA & 0xFFFF0000u)); \
      const unsigned lB = cvt_pk(h2n[2] - __uint_as_float(hB << 16),          \
                                 h2n[3] - __uint_as_float(hB & 0xFFFF0000u)); \
      *(uint2*)(smem + H2((S) & 1, 0) + hwr0) = make_uint2(hA, hB);           \
      *(uint2*)(smem + H2((S) & 1, 1) + hwr0) = make_uint2(lA, lB);           \
      if ((KK) >= 3) {                                                        \
        float pw = wlinc[0] * h2n[0];                                         \
        pw = fmaf(wlinc[1], h2n[1], pw);                                      \
        pw = fmaf(wlinc[2], h2n[2], pw);                                      \
        pw = fmaf(wlinc[3], h2n[3], pw);                                      \
        pw += __shfl_xor(pw, 16, 64);                                         \
        pw += __shfl_xor(pw, 32, 64);                                         \
        if (g == 0) *(float*)(ringb + (((KK) - 3) & 127) * 256) = pw;         \
      }                                                                       \
    }                                                                         \
  }

#pragma unroll 1
    for (int kb = 0; kb < 512; kb += 4) {
      OB(kb + 0, 0);
      __syncthreads();
      OB(kb + 1, 1);
      __syncthreads();
      OB(kb + 2, 2);
      __syncthreads();
      OB(kb + 3, 3);
      __syncthreads();
    }
    OB(512, 0);
    __syncthreads();
    OB(513, 1);
    __syncthreads();
    // ---- tail flush: out positions 448..510 ----
    {
      const int thr = ow * 64 + lane;
      for (int e = thr; e < 63 * 16; e += 256) {
        const int ss2 = e & 15, off = e >> 4;
        const int idx = 448 + off;
        const char* op = smem + RING + (idx & 127) * 256 + ss2 * 4;
        const float v = *(const float*)(op) + *(const float*)(op + 64) +
                        *(const float*)(op + 128) + *(const float*)(op + 192) + bl0;
        out[(size_t)(s0 + ss2) * 511 + idx] = v;
      }
    }
  }
}

extern "C" void kernel_launch(void* const* d_in, const int* in_sizes, int n_in,
                              void* d_out, int out_size, void* d_ws, size_t ws_size,
                              hipStream_t stream) {
  const float* y    = (const float*)d_in[0];
  const float* Wih1 = (const float*)d_in[1];
  const float* Whh1 = (const float*)d_in[2];
  const float* bih1 = (const float*)d_in[3];
  const float* bhh1 = (const float*)d_in[4];
  const float* Wih2 = (const float*)d_in[5];
  const float* Whh2 = (const float*)d_in[6];
  const float* bih2 = (const float*)d_in[7];
  const float* bhh2 = (const float*)d_in[8];
  const float* Wlin = (const float*)d_in[9];
  const float* blin = (const float*)d_in[10];
  float* out = (float*)d_out;

  hipFuncSetAttribute((const void*)lstm2_r14,
                      hipFuncAttributeMaxDynamicSharedMemorySize, LDS_BYTES);
  lstm2_r14<<<dim3(128), dim3(512), LDS_BYTES, stream>>>(
      y, Wih1, Whh1, bih1, bhh1, Wih2, Whh2, bih2, bhh2, Wlin, blin, out);
}

// Round 15
// 564.900 us; speedup vs baseline: 1.1390x; 1.1390x over previous
//
#include <hip/hip_runtime.h>

// 2-layer LSTM (H=64, D=1), N=2048, T=512 — R15: i8 2-LEVEL FIXED-POINT MFMA.
// Structure = R13 champion verbatim (128 blocks x 512 thr, E waves 0-3 = L1
// step k, O waves 4-7 = L2 step k-1, one __syncthreads per step, parity
// double-buffered planes, 128-slot out ring). Numeric core replaced:
//   W = W0*2^-9 + W1*2^-17 (i8,i8; |W|<1/8 so W0 fits), h = h0*2^-6+h1*2^-14.
//   gate = S00*2^-15 + SB*2^-23 (+bias,x in f32), where
//     S00 = sum W0*h0 (i32 exact), SB = sum (W0*h1 + W1*h0) (shared scale).
//   mfma_i32_16x16x64_i8: K=64 in ONE instruction -> 3 MFMAs per matvec
//   (vs 6 bf16) => per-SIMD matrix issue halves; h planes are i8 (1 b128
//   per level covers K=64) => LDS reads halve.
// exp2-prescale retained (gsc folded into combine scales / bias / wih1).

typedef __attribute__((ext_vector_type(4))) int i32x4;
typedef __attribute__((ext_vector_type(4))) float f32x4;

#define XPITCH 2060              // 515 words (odd) -> conflict-free x reads
#define XP 0                     // 16 * 2060 = 32960
#define HB 32960                 // 8 planes x 1280 = 10240
// plane(layer 0=h1/1=h2, parity P, level L): [16 s][pitch 80], row r at byte s*80+r
#define HPL(layer, P, L) (HB + ((((layer) * 2 + (P)) * 2) + (L)) * 1280)
#define RING 43200               // 128 slots * 256 B
#define LDS_BYTES 75968
#define L2E 1.44269504f
#define N2L2E (-2.8853900817779268f)

__device__ __forceinline__ float fast_rcp(float x) { return __builtin_amdgcn_rcpf(x); }
__device__ __forceinline__ float exp2_f(float x) {
  float r; asm("v_exp_f32 %0, %1" : "=v"(r) : "v"(x)); return r;
}
__device__ __forceinline__ i32x4 mfma_i8(i32x4 a, i32x4 b, i32x4 c) {
  return __builtin_amdgcn_mfma_i32_16x16x64_i8(a, b, c, 0, 0, 0);
}
// gates pre-scaled: i,f,o by log2e; g by 2log2e. 5 exp2 + 3 rcp.
__device__ __forceinline__ void cell2(float i, float f, float g, float o,
                                      float& c, float& h) {
  const float ei = exp2_f(-i), ef = exp2_f(-f), eg = exp2_f(-g), eo = exp2_f(-o);
  const float P = (1.f - eg) * fast_rcp((1.f + ei) * (1.f + eg));
  c = fmaf(c, fast_rcp(1.f + ef), P);
  const float cc = fminf(15.f, fmaxf(-15.f, c));
  const float ec = exp2_f(N2L2E * cc);
  h = (1.f - ec) * fast_rcp((1.f + eo) * (1.f + ec));
}
// Quantize 16 consecutive f32 weights (|W|<1/8) to two i8 levels, packed.
__device__ __forceinline__ void quantW16(const float* p, i32x4& w0v, i32x4& w1v) {
  int b0[16], b1[16];
#pragma unroll
  for (int e = 0; e < 16; ++e) {
    const float v = p[e];
    const float q0 = rintf(v * 512.f);
    const float r = v - q0 * (1.f / 512.f);
    const float q1 = fminf(127.f, fmaxf(-127.f, rintf(r * 131072.f)));
    b0[e] = (int)q0;
    b1[e] = (int)q1;
  }
#pragma unroll
  for (int d = 0; d < 4; ++d) {
    w0v[d] = (b0[4 * d] & 255) | ((b0[4 * d + 1] & 255) << 8) |
             ((b0[4 * d + 2] & 255) << 16) | ((b0[4 * d + 3] & 255) << 24);
    w1v[d] = (b1[4 * d] & 255) | ((b1[4 * d + 1] & 255) << 8) |
             ((b1[4 * d + 2] & 255) << 16) | ((b1[4 * d + 3] & 255) << 24);
  }
}
// Quantize 4 h values (|h|<=1) to two packed i8-level dwords.
__device__ __forceinline__ void quantH4(const float* h, unsigned& L0, unsigned& L1) {
  int q0[4], q1[4];
#pragma unroll
  for (int r = 0; r < 4; ++r) {
    const float q0f = rintf(h[r] * 64.f);
    q0[r] = (int)q0f;
    const float rr = h[r] - q0f * 0.015625f;
    const float q1f = fminf(127.f, fmaxf(-127.f, rintf(rr * 16384.f)));
    q1[r] = (int)q1f;
  }
  L0 = (q0[0] & 255) | ((q0[1] & 255) << 8) | ((q0[2] & 255) << 16) |
       ((q0[3] & 255) << 24);
  L1 = (q1[0] & 255) | ((q1[1] & 255) << 8) | ((q1[2] & 255) << 16) |
       ((q1[3] & 255) << 24);
}

__global__ __launch_bounds__(512, 2) void lstm2_r15(
    const float* __restrict__ y, const float* __restrict__ Wih1,
    const float* __restrict__ Whh1, const float* __restrict__ bih1,
    const float* __restrict__ bhh1, const float* __restrict__ Wih2,
    const float* __restrict__ Whh2, const float* __restrict__ bih2,
    const float* __restrict__ bhh2, const float* __restrict__ Wlin,
    const float* __restrict__ blin, float* __restrict__ out) {
  extern __shared__ char smem[];
  const int tid = threadIdx.x;
  const int w = tid >> 6;          // wave 0..7
  const int lane = tid & 63;
  const int g = lane >> 4;
  const int s = lane & 15;
  const int s0 = blockIdx.x * 16;

  for (int i = tid; i < 16 * 512; i += 512) {
    const int ss = i >> 9, t = i & 511;
    *(float*)(smem + XP + ss * XPITCH + t * 4) = y[(size_t)(s0 + ss) * 512 + t];
  }
  for (int i = tid; i < 10240 / 4; i += 512) *(float*)(smem + HB + i * 4) = 0.f;
  const float bl0 = blin[0];
  __syncthreads();

  const int boff = s * 80 + 16 * g;              // B-fragment byte offset in plane
  const float gsc[4] = {L2E, L2E, 2.0f * L2E, L2E};
  const i32x4 zeroi = {0, 0, 0, 0};
  float sc00[4], scB[4];
#pragma unroll
  for (int p = 0; p < 4; ++p) {
    sc00[p] = gsc[p] * (1.f / 32768.f);          // 2^-15
    scB[p] = gsc[p] * (1.f / 8388608.f);         // 2^-23
  }

  if (w < 4) {
    // =================== E: layer 1, step k ===================
    const int row = 16 * w + s;
    i32x4 aW0[4], aW1[4];
#pragma unroll
    for (int p = 0; p < 4; ++p)
      quantW16(Whh1 + (size_t)(p * 64 + row) * 64 + 16 * g, aW0[p], aW1[p]);
    float bias1c[4][4], wih1c[4][4];
#pragma unroll
    for (int p = 0; p < 4; ++p)
#pragma unroll
      for (int r = 0; r < 4; ++r) {
        const int rr = p * 64 + 16 * w + 4 * g + r;
        bias1c[p][r] = (bih1[rr] + bhh1[rr]) * gsc[p];
        wih1c[p][r] = Wih1[rr] * gsc[p];
      }
    float c1[4] = {0.f, 0.f, 0.f, 0.f};
    const int hwA = s * 80 + 16 * w + 4 * g;     // h-write byte offset in plane
    const float* xrow = (const float*)(smem + XP + s * XPITCH);

#define EB(KK, P)                                                             \
  {                                                                           \
    const float x = xrow[KK];                                                 \
    const i32x4 B0 = *(const i32x4*)(smem + HPL(0, (P) ^ 1, 0) + boff);       \
    const i32x4 B1 = *(const i32x4*)(smem + HPL(0, (P) ^ 1, 1) + boff);       \
    i32x4 S00[4], SB[4];                                                      \
    __builtin_amdgcn_s_setprio(1);                                            \
    _Pragma("unroll") for (int p = 0; p < 4; ++p)                             \
        S00[p] = mfma_i8(aW0[p], B0, zeroi);                                  \
    _Pragma("unroll") for (int p = 0; p < 4; ++p)                             \
        SB[p] = mfma_i8(aW1[p], B0, zeroi);                                   \
    _Pragma("unroll") for (int p = 0; p < 4; ++p)                             \
        SB[p] = mfma_i8(aW0[p], B1, SB[p]);                                   \
    __builtin_amdgcn_s_setprio(0);                                            \
    float ga[4][4];                                                           \
    _Pragma("unroll") for (int p = 0; p < 4; ++p) {                           \
      _Pragma("unroll") for (int r = 0; r < 4; ++r) {                         \
        float base = fmaf(wih1c[p][r], x, bias1c[p][r]);                      \
        base = fmaf((float)SB[p][r], scB[p], base);                           \
        ga[p][r] = fmaf((float)S00[p][r], sc00[p], base);                     \
      }                                                                       \
    }                                                                         \
    float h1n[4];                                                             \
    _Pragma("unroll") for (int r = 0; r < 4; ++r)                             \
        cell2(ga[0][r], ga[1][r], ga[2][r], ga[3][r], c1[r], h1n[r]);         \
    unsigned L0, L1;                                                          \
    quantH4(h1n, L0, L1);                                                     \
    *(unsigned*)(smem + HPL(0, (P), 0) + hwA) = L0;                           \
    *(unsigned*)(smem + HPL(0, (P), 1) + hwA) = L1;                           \
  }

    EB(0, 0);
    __syncthreads();
#pragma unroll 1
    for (int kb = 1; kb <= 509; kb += 2) {
      EB(kb, 1);
      __syncthreads();
      EB(kb + 1, 0);
      __syncthreads();
    }
    EB(511, 1);
    __syncthreads();
    __syncthreads();  // iter 512 (E idle; O computes h2(511))
  } else {
    // =================== O: layer 2, step k-1 ===================
    const int ow = w - 4;
    const int row = 16 * ow + s;
    i32x4 bW0[4], bW1[4], cW0[4], cW1[4];
#pragma unroll
    for (int p = 0; p < 4; ++p) {
      quantW16(Wih2 + (size_t)(p * 64 + row) * 64 + 16 * g, bW0[p], bW1[p]);
      quantW16(Whh2 + (size_t)(p * 64 + row) * 64 + 16 * g, cW0[p], cW1[p]);
    }
    float bias2c[4][4], wlinc[4];
#pragma unroll
    for (int p = 0; p < 4; ++p)
#pragma unroll
      for (int r = 0; r < 4; ++r) {
        const int rr = p * 64 + 16 * ow + 4 * g + r;
        bias2c[p][r] = (bih2[rr] + bhh2[rr]) * gsc[p];
      }
#pragma unroll
    for (int r = 0; r < 4; ++r) wlinc[r] = Wlin[16 * ow + 4 * g + r];
    float c2[4] = {0.f, 0.f, 0.f, 0.f};
    const int hwA = s * 80 + 16 * ow + 4 * g;
    char* ringb = smem + RING + ow * 64 + s * 4;

#define OFLUSH(KK)                                                            \
  if ((KK) >= 66 && (((KK)-2) & 63) == 0) {                                   \
    const int base = (KK)-66;                                                 \
    const int thr = ow * 64 + lane;                                           \
    const int ss2 = thr & 15, grp = thr >> 4;                                 \
    _Pragma("unroll") for (int q = 0; q < 4; ++q) {                           \
      const int idx = base + grp * 4 + q;                                     \
      const char* op = smem + RING + (idx & 127) * 256 + ss2 * 4;             \
      const float v = *(const float*)(op) + *(const float*)(op + 64) +        \
                      *(const float*)(op + 128) + *(const float*)(op + 192) + \
                      bl0;                                                    \
      out[(size_t)(s0 + ss2) * 511 + idx] = v;                                \
    }                                                                         \
  }

#define OB(KK, P)                                                             \
  {                                                                           \
    const i32x4 B10 = *(const i32x4*)(smem + HPL(0, (P) ^ 1, 0) + boff);      \
    const i32x4 B11 = *(const i32x4*)(smem + HPL(0, (P) ^ 1, 1) + boff);      \
    const i32x4 B20 = *(const i32x4*)(smem + HPL(1, (P), 0) + boff);          \
    const i32x4 B21 = *(const i32x4*)(smem + HPL(1, (P), 1) + boff);          \
    i32x4 S00[4], SB[4];                                                      \
    __builtin_amdgcn_s_setprio(1);                                            \
    _Pragma("unroll") for (int p = 0; p < 4; ++p)                             \
        S00[p] = mfma_i8(bW0[p], B10, zeroi);                                 \
    _Pragma("unroll") for (int p = 0; p < 4; ++p)                             \
        SB[p] = mfma_i8(bW1[p], B10, zeroi);                                  \
    _Pragma("unroll") for (int p = 0; p < 4; ++p)                             \
        S00[p] = mfma_i8(cW0[p], B20, S00[p]);                                \
    _Pragma("unroll") for (int p = 0; p < 4; ++p)                             \
        SB[p] = mfma_i8(bW0[p], B11, SB[p]);                                  \
    _Pragma("unroll") for (int p = 0; p < 4; ++p)                             \
        SB[p] = mfma_i8(cW1[p], B20, SB[p]);                                  \
    _Pragma("unroll") for (int p = 0; p < 4; ++p)                             \
        SB[p] = mfma_i8(cW0[p], B21, SB[p]);                                  \
    __builtin_amdgcn_s_setprio(0);                                            \
    float ga[4][4];                                                           \
    _Pragma("unroll") for (int p = 0; p < 4; ++p) {                           \
      _Pragma("unroll") for (int r = 0; r < 4; ++r) {                         \
        float base = fmaf((float)SB[p][r], scB[p], bias2c[p][r]);             \
        ga[p][r] = fmaf((float)S00[p][r], sc00[p], base);                     \
      }                                                                       \
    }                                                                         \
    float h2n[4];                                                             \
    _Pragma("unroll") for (int r = 0; r < 4; ++r)                             \
        cell2(ga[0][r], ga[1][r], ga[2][r], ga[3][r], c2[r], h2n[r]);         \
    unsigned L0, L1;                                                          \
    quantH4(h2n, L0, L1);                                                     \
    *(unsigned*)(smem + HPL(1, (P) ^ 1, 0) + hwA) = L0;                       \
    *(unsigned*)(smem + HPL(1, (P) ^ 1, 1) + hwA) = L1;                       \
    if ((KK) >= 2) {                                                          \
      float pw = wlinc[0] * h2n[0];                                           \
      pw = fmaf(wlinc[1], h2n[1], pw);                                        \
      pw = fmaf(wlinc[2], h2n[2], pw);                                        \
      pw = fmaf(wlinc[3], h2n[3], pw);                                        \
      pw += __shfl_xor(pw, 16, 64);                                           \
      pw += __shfl_xor(pw, 32, 64);                                           \
      if (g == 0) *(float*)(ringb + (((KK)-2) & 127) * 256) = pw;             \
    }                                                                         \
  }

    __syncthreads();  // k = 0 (O idle)
#pragma unroll 1
    for (int kb = 1; kb <= 509; kb += 2) {
      OB(kb, 1);
      __syncthreads();
      OFLUSH(kb + 1);
      OB(kb + 1, 0);
      __syncthreads();
    }
    OB(511, 1);
    __syncthreads();
    OB(512, 0);
    __syncthreads();
    // tail flush: out positions 448..510
    {
      const int thr = ow * 64 + lane;
      for (int e = thr; e < 63 * 16; e += 256) {
        const int ss2 = e & 15, off = e >> 4;
        const int idx = 448 + off;
        const char* op = smem + RING + (idx & 127) * 256 + ss2 * 4;
        const float v = *(const float*)(op) + *(const float*)(op + 64) +
                        *(const float*)(op + 128) + *(const float*)(op + 192) + bl0;
        out[(size_t)(s0 + ss2) * 511 + idx] = v;
      }
    }
  }
}

extern "C" void kernel_launch(void* const* d_in, const int* in_sizes, int n_in,
                              void* d_out, int out_size, void* d_ws, size_t ws_size,
                              hipStream_t stream) {
  const float* y    = (const float*)d_in[0];
  const float* Wih1 = (const float*)d_in[1];
  const float* Whh1 = (const float*)d_in[2];
  const float* bih1 = (const float*)d_in[3];
  const float* bhh1 = (const float*)d_in[4];
  const float* Wih2 = (const float*)d_in[5];
  const float* Whh2 = (const float*)d_in[6];
  const float* bih2 = (const float*)d_in[7];
  const float* bhh2 = (const float*)d_in[8];
  const float* Wlin = (const float*)d_in[9];
  const float* blin = (const float*)d_in[10];
  float* out = (float*)d_out;

  hipFuncSetAttribute((const void*)lstm2_r15,
                      hipFuncAttributeMaxDynamicSharedMemorySize, LDS_BYTES);
  lstm2_r15<<<dim3(128), dim3(512), LDS_BYTES, stream>>>(
      y, Wih1, Whh1, bih1, bhh1, Wih2, Whh2, bih2, bhh2, Wlin, blin, out);
}